// Round 9
// baseline (206.108 us; speedup 1.0000x reference)
//
#include <hip/hip_runtime.h>

// ---------------------------------------------------------------------------
// ConvFeatureExtractor: profile = rownorm( freq @ softmax(matches/T, axis=1)^T )
//   matches[f,i] = Thi[f,i>>6] + Tlo[f,i&63] (separable) => probs = e1 x e2.
// R9: barrier-free GEMM. Double factorization:
//   pooled[b,f] = sum_h e1'[f,h] * ( sum_l A[b,h*64+l] * bf16(e2[f,l]) )
//   - B-fragments = bf16(e2): CONSTANT over K -> 16 frags precomputed in regs
//   - e1'[f,kt] scales the per-kt MFMA partial via 32 v_fma (C-layout col=f)
//   - waves split on M (16 rows each, no sharing) -> A-frags loaded straight
//     from global/L2; NO LDS, NO __syncthreads in the K-loop. kt+1 prefetch.
//   R8 evidence: the ~80us plateau is the barrier+LDS drain (occupancy R4/R6,
//   staging R5, barrier-count R8 all dead) - so the structure goes.
// ---------------------------------------------------------------------------

typedef __bf16  bf16x8 __attribute__((ext_vector_type(8)));
typedef float   f32x4  __attribute__((ext_vector_type(4)));

__device__ __forceinline__ short f2bf(float x) {
  unsigned u = __float_as_uint(x);
  unsigned r = (u + 0x7fffu + ((u >> 16) & 1u)) >> 16;   // RNE
  return (short)r;
}

__device__ __forceinline__ float wave_max(float v) {
  #pragma unroll
  for (int off = 32; off; off >>= 1) v = fmaxf(v, __shfl_xor(v, off, 64));
  return v;
}
__device__ __forceinline__ float wave_sum(float v) {
  #pragma unroll
  for (int off = 32; off; off >>= 1) v += __shfl_xor(v, off, 64);
  return v;
}

// ---------------- k1: prep = cast (blocks 0..4095) + tables (blocks 4096..4223)
__global__ __launch_bounds__(256) void prep_kernel(const float* __restrict__ freq,
                                                   const float* __restrict__ kp,
                                                   const float* __restrict__ temp,
                                                   short* __restrict__ freqb,
                                                   float* __restrict__ E1t,
                                                   float* __restrict__ E2) {
  __shared__ float E1loc[64][64];
  __shared__ float E2loc[64][64];
  const int blk = blockIdx.x;
  const int t = threadIdx.x;

  if (blk < 4096) {                     // ---- cast part: freq f32 -> bf16
    int idx = blk * 256 + t;
    float4 v = ((const float4*)freq)[idx];
    short4 o;
    o.x = f2bf(v.x); o.y = f2bf(v.y); o.z = f2bf(v.z); o.w = f2bf(v.w);
    ((short4*)freqb)[idx] = o;
    return;
  }

  // ---- tables part: block bb handles 64 filters
  const int bb = blk - 4096;            // 0..127
  const int f0 = bb * 64;
  const int lane = t & 63, wave = t >> 6;
  const float invT = 1.0f / temp[0];
  const int d0 = (lane >> 4) & 3, d1 = (lane >> 2) & 3, d2 = lane & 3;

  #pragma unroll
  for (int ffi = 0; ffi < 16; ffi++) {
    const int floc = wave * 16 + ffi;
    const float* P = kp + (size_t)(f0 + floc) * 24;
    const float thi = P[d0 * 6 + 0] + P[d1 * 6 + 1] + P[d2 * 6 + 2];
    const float tlo = P[d0 * 6 + 3] + P[d1 * 6 + 4] + P[d2 * 6 + 5];
    const float mxhi = wave_max(thi), mxlo = wave_max(tlo);
    const float e1 = __expf((thi - mxhi) * invT);
    const float e2 = __expf((tlo - mxlo) * invT);
    const float s1 = wave_sum(e1), s2 = wave_sum(e2);
    const float invZ = 1.0f / (s1 * s2);
    E1loc[floc][lane] = e1 * invZ;     // lane indexes h (high digits)
    E2loc[floc][lane] = e2;            // lane indexes l (low digits)
  }
  __syncthreads();

  // E1t[h][f] coalesced write via transpose
  {
    const int h = t >> 2, c0 = (t & 3) * 16;
    float tmp[16];
    #pragma unroll
    for (int cc = 0; cc < 16; cc++) tmp[cc] = E1loc[c0 + cc][h];
    float* dst = E1t + (size_t)h * 8192 + f0 + c0;
    #pragma unroll
    for (int q = 0; q < 4; q++)
      ((f32x4*)dst)[q] = (f32x4){tmp[q*4], tmp[q*4+1], tmp[q*4+2], tmp[q*4+3]};
  }
  // E2[f][l] coalesced write
  {
    const int fl = t >> 2, l0 = (t & 3) * 16;
    float* dst = E2 + (size_t)(f0 + fl) * 64 + l0;
    #pragma unroll
    for (int q = 0; q < 4; q++)
      ((f32x4*)dst)[q] = *(const f32x4*)&E2loc[fl][l0 + q * 4];
  }
}

// ---------------- k2: barrier-free GEMM ----------------
// grid (64 n-tiles, 16 m-tiles), 256 thr. Wave w owns rows mw = m0+w*16,
// all 128 n (8 j-frags). No LDS. Per kt: 2 direct A-frag loads + 8 e1 loads,
// 16 MFMA (P partial, C=zero chain), 32 v_fma (acc += e1*P).
__global__ __launch_bounds__(256, 3) void gemm_kernel(const short* __restrict__ A,
                                                      const float* __restrict__ E1t,
                                                      const float* __restrict__ E2,
                                                      float* __restrict__ C) {
  const int t = threadIdx.x;
  const int lane = t & 63, wave = t >> 6;
  const int quad = lane >> 4, l16 = lane & 15;
  const int n0 = blockIdx.x * 128;
  const int mw = blockIdx.y * 64 + wave * 16;    // wave's m-rows

  // constant B-fragments: bfr[j][ks] = bf16(e2[n0+j*16+l16][ks*32+quad*8 ..+8])
  bf16x8 bfr[8][2];
  #pragma unroll
  for (int j = 0; j < 8; j++)
    #pragma unroll
    for (int ks = 0; ks < 2; ks++) {
      const float* p = E2 + (size_t)(n0 + j * 16 + l16) * 64 + ks * 32 + quad * 8;
      float4 lo = *(const float4*)p;
      float4 hi = *(const float4*)(p + 4);
      bf16x8 bb;
      bb[0] = (__bf16)lo.x; bb[1] = (__bf16)lo.y; bb[2] = (__bf16)lo.z; bb[3] = (__bf16)lo.w;
      bb[4] = (__bf16)hi.x; bb[5] = (__bf16)hi.y; bb[6] = (__bf16)hi.z; bb[7] = (__bf16)hi.w;
      bfr[j][ks] = bb;
    }

  f32x4 acc[8];
  #pragma unroll
  for (int j = 0; j < 8; j++) acc[j] = (f32x4){0.f, 0.f, 0.f, 0.f};
  const f32x4 zf = (f32x4){0.f, 0.f, 0.f, 0.f};

  const short* Arow  = A + (size_t)(mw + l16) * 4096 + quad * 8;  // + kt*64 + ks*32
  const float* E1b   = E1t + n0 + l16;                            // + kt*8192 + j*16

  // prefetch kt=0
  bf16x8 a0 = *(const bf16x8*)(Arow);
  bf16x8 a1 = *(const bf16x8*)(Arow + 32);
  float e1v[8];
  #pragma unroll
  for (int j = 0; j < 8; j++) e1v[j] = E1b[j * 16];

  for (int kt = 0; kt < 64; kt++) {
    // prefetch kt+1 (clamped; redundant loads on last iter are harmless)
    const int ktn = (kt < 63) ? kt + 1 : 63;
    bf16x8 na0 = *(const bf16x8*)(Arow + ktn * 64);
    bf16x8 na1 = *(const bf16x8*)(Arow + ktn * 64 + 32);
    float ne1[8];
    #pragma unroll
    for (int j = 0; j < 8; j++) ne1[j] = E1b[(size_t)ktn * 8192 + j * 16];

    #pragma unroll
    for (int j = 0; j < 8; j++) {
      f32x4 P = __builtin_amdgcn_mfma_f32_16x16x32_bf16(a0, bfr[j][0], zf, 0, 0, 0);
      P = __builtin_amdgcn_mfma_f32_16x16x32_bf16(a1, bfr[j][1], P, 0, 0, 0);
      const float s = e1v[j];
      acc[j][0] += s * P[0];
      acc[j][1] += s * P[1];
      acc[j][2] += s * P[2];
      acc[j][3] += s * P[3];
    }

    a0 = na0; a1 = na1;
    #pragma unroll
    for (int j = 0; j < 8; j++) e1v[j] = ne1[j];
  }

  // epilogue: C/D layout col=lane&15 (n), row=quad*4+r (m within 16)
  #pragma unroll
  for (int r = 0; r < 4; r++) {
    float* crow = C + (size_t)(mw + quad * 4 + r) * 8192 + n0 + l16;
    #pragma unroll
    for (int j = 0; j < 8; j++) crow[j * 16] = acc[j][r];
  }
}

// ---------------- k3: row-normalize d_out (1024 rows of 8192) ----------------
__global__ __launch_bounds__(256) void norm_kernel(float* __restrict__ out) {
  const int b = blockIdx.x;
  const int t = threadIdx.x;
  const int lane = t & 63, wave = t >> 6;
  __shared__ float red[4];

  float4* row = (float4*)(out + (size_t)b * 8192);   // 2048 float4
  float4 v[8];
  float s = 0.0f;
  #pragma unroll
  for (int q = 0; q < 8; q++) {
    v[q] = row[q * 256 + t];
    s += (v[q].x + v[q].y) + (v[q].z + v[q].w);
  }
  float ws = wave_sum(s);
  if (lane == 0) red[wave] = ws;
  __syncthreads();
  float tot = (red[0] + red[1]) + (red[2] + red[3]);
  float inv = 1.0f / tot;
  #pragma unroll
  for (int q = 0; q < 8; q++) {
    v[q].x *= inv; v[q].y *= inv; v[q].z *= inv; v[q].w *= inv;
    row[q * 256 + t] = v[q];
  }
}

// ---------------------------------------------------------------------------
extern "C" void kernel_launch(void* const* d_in, const int* in_sizes, int n_in,
                              void* d_out, int out_size, void* d_ws, size_t ws_size,
                              hipStream_t stream) {
  const float* freq    = (const float*)d_in[0];   // 1024*4096
  const float* kparams = (const float*)d_in[1];   // 8192*4*6
  const float* temp    = (const float*)d_in[2];   // 1
  // d_in[3] = kmer_idcs (recomputed analytically in-kernel)

  float* out = (float*)d_out;                     // 1024*8192 f32

  short* freqb = (short*)d_ws;                           // 8 MiB
  float* E1t   = (float*)(freqb + (size_t)1024 * 4096);  // 64*8192 f32 = 2 MiB
  float* E2    = E1t + (size_t)64 * 8192;                // 8192*64 f32 = 2 MiB

  prep_kernel<<<4224, 256, 0, stream>>>(freq, kparams, temp, freqb, E1t, E2);
  gemm_kernel<<<dim3(64, 16), 256, 0, stream>>>(freqb, E1t, E2, out);
  norm_kernel<<<1024, 256, 0, stream>>>(out);
}